// Round 9
// baseline (245.307 us; speedup 1.0000x reference)
//
#include <hip/hip_runtime.h>
#include <math.h>

#define BATCH   2048
#define NPTS    4096
#define THREADS 256
#define CHUNKS  4                    // blocks per batch
#define CPTS    (NPTS / CHUNKS)      // 1024 points per block
#define WTHRESH 0.5f
#define EPS     1e-5

// ---------------------------------------------------------------------------
// Async global->LDS 16B copy (wave-uniform LDS base + lane*16; per-lane
// global address). Our linear layout matches the HW rule exactly.
// ---------------------------------------------------------------------------
__device__ __forceinline__ void async_ld16(const void* g, void* l) {
  __builtin_amdgcn_global_load_lds((const __attribute__((address_space(1))) void*)g,
                                   (__attribute__((address_space(3))) void*)l, 16, 0, 0);
}

// Block-wide reduction of 16 floats; valid in acc[] of thread 0 afterwards.
__device__ __forceinline__ void reduce_block16(float* acc, float* red /*64 floats*/) {
#pragma unroll
  for (int off = 32; off > 0; off >>= 1) {
#pragma unroll
    for (int i = 0; i < 16; ++i) acc[i] += __shfl_down(acc[i], off, 64);
  }
  const int wave = threadIdx.x >> 6;
  const int lane = threadIdx.x & 63;
  if (lane == 0) {
#pragma unroll
    for (int i = 0; i < 16; ++i) red[wave * 16 + i] = acc[i];
  }
  __syncthreads();
  if (threadIdx.x == 0) {
#pragma unroll
    for (int w = 1; w < 4; ++w)
#pragma unroll
      for (int i = 0; i < 16; ++i) acc[i] += red[w * 16 + i];
  }
}

// ---------------------------------------------------------------------------
// Accumulate 16 sufficient statistics for 4 points given their registers.
// acc: [0]=W [1..3]=sum w*src [4..6]=sum w*tgt [7..15]=sum w*src_i*tgt_j
// ---------------------------------------------------------------------------
__device__ __forceinline__ void accum_pts(float4 w4, float4 s0, float4 s1, float4 s2,
                                          float4 r0, float4 r1, float4 r2, float* acc) {
  float ww[4] = {w4.x, w4.y, w4.z, w4.w};
  float ps[4][3] = {{s0.x, s0.y, s0.z}, {s0.w, s1.x, s1.y},
                    {s1.z, s1.w, s2.x}, {s2.y, s2.z, s2.w}};
  float qs[4][3] = {{r0.x, r0.y, r0.z}, {r0.w, r1.x, r1.y},
                    {r1.z, r1.w, r2.x}, {r2.y, r2.z, r2.w}};
#pragma unroll
  for (int i = 0; i < 4; ++i) {
    float w = (ww[i] < WTHRESH) ? 0.f : ww[i];
    acc[0] += w;
    float wp0 = w * ps[i][0], wp1 = w * ps[i][1], wp2 = w * ps[i][2];
    acc[1] += wp0; acc[2] += wp1; acc[3] += wp2;
    acc[4] += w * qs[i][0]; acc[5] += w * qs[i][1]; acc[6] += w * qs[i][2];
    acc[7]  += wp0 * qs[i][0]; acc[8]  += wp0 * qs[i][1]; acc[9]  += wp0 * qs[i][2];
    acc[10] += wp1 * qs[i][0]; acc[11] += wp1 * qs[i][1]; acc[12] += wp1 * qs[i][2];
    acc[13] += wp2 * qs[i][0]; acc[14] += wp2 * qs[i][1]; acc[15] += wp2 * qs[i][2];
  }
}

// ---------------------------------------------------------------------------
// fp64 3x3 Kabsch solve — FULLY SCALARIZED (no arrays, no runtime indexing,
// no scratch; rule #20). Jacobi rotations unrolled per-pair as macros with
// branchless selects; eigen-sort as explicit register compare-swaps.
// R = v1 u1^T + v2 u2^T + det(V) * v3 (u1 x u2)^T
// ---------------------------------------------------------------------------

// One Jacobi rotation for pair (p,q), third index t (symmetric A, V=V*J).
// app,aqq,apq,apt,aqt are the affected A entries; vpK/vqK are V[row K][p/q].
#define JROT(app, aqq, apq, apt, aqt, vp0, vq0, vp1, vq1, vp2, vq2)            \
  {                                                                            \
    bool go = fabs(apq) > 1e-300;                                              \
    double apq_s = go ? apq : 1.0;                                             \
    double theta = (aqq - app) / (2.0 * apq_s);                                \
    double tt = copysign(1.0, theta) / (fabs(theta) + sqrt(theta*theta + 1.0));\
    double cc = 1.0 / sqrt(tt*tt + 1.0);                                       \
    double ss = tt * cc;                                                       \
    cc = go ? cc : 1.0; ss = go ? ss : 0.0;                                    \
    double app_n = cc*cc*app - 2.0*cc*ss*apq + ss*ss*aqq;                      \
    double aqq_n = ss*ss*app + 2.0*cc*ss*apq + cc*cc*aqq;                      \
    double apt_n = cc*apt - ss*aqt;                                            \
    double aqt_n = ss*apt + cc*aqt;                                            \
    app = app_n; aqq = aqq_n; apq = 0.0; apt = apt_n; aqt = aqt_n;             \
    double tv;                                                                 \
    tv = vp0; vp0 = cc*tv - ss*vq0; vq0 = ss*tv + cc*vq0;                      \
    tv = vp1; vp1 = cc*tv - ss*vq1; vq1 = ss*tv + cc*vq1;                      \
    tv = vp2; vp2 = cc*tv - ss*vq2; vq2 = ss*tv + cc*vq2;                      \
  }

// Compare-swap (descending) of eigenvalue pair + their V columns.
#define CSWAP(ea, eb, x0, y0, x1, y1, x2, y2)                                  \
  { bool sw = ea < eb; double td;                                              \
    td = ea; ea = sw ? eb : ea; eb = sw ? td : eb;                             \
    td = x0; x0 = sw ? y0 : x0; y0 = sw ? td : y0;                             \
    td = x1; x1 = sw ? y1 : x1; y1 = sw ? td : y1;                             \
    td = x2; x2 = sw ? y2 : x2; y2 = sw ? td : y2; }

__device__ void solve_from_acc(const float* acc, float* R9, float* t3) {
  const double W = acc[0];
  const double inv = 1.0 / (W + EPS);
  const double sc0 = acc[1] * inv, sc1 = acc[2] * inv, sc2 = acc[3] * inv;
  const double tc0 = acc[4] * inv, tc1 = acc[5] * inv, tc2 = acc[6] * inv;
  const double f = 2.0 - W * inv;

  const double h00 = acc[7]  * inv - sc0 * tc0 * f;
  const double h01 = acc[8]  * inv - sc0 * tc1 * f;
  const double h02 = acc[9]  * inv - sc0 * tc2 * f;
  const double h10 = acc[10] * inv - sc1 * tc0 * f;
  const double h11 = acc[11] * inv - sc1 * tc1 * f;
  const double h12 = acc[12] * inv - sc1 * tc2 * f;
  const double h20 = acc[13] * inv - sc2 * tc0 * f;
  const double h21 = acc[14] * inv - sc2 * tc1 * f;
  const double h22 = acc[15] * inv - sc2 * tc2 * f;

  // A = H^T H (symmetric): a_ij = sum_k h_ki h_kj
  double a00 = h00*h00 + h10*h10 + h20*h20;
  double a01 = h00*h01 + h10*h11 + h20*h21;
  double a02 = h00*h02 + h10*h12 + h20*h22;
  double a11 = h01*h01 + h11*h11 + h21*h21;
  double a12 = h01*h02 + h11*h12 + h21*h22;
  double a22 = h02*h02 + h12*h12 + h22*h22;

  double v00 = 1, v01 = 0, v02 = 0;
  double v10 = 0, v11 = 1, v12 = 0;
  double v20 = 0, v21 = 0, v22 = 1;

  // Cyclic Jacobi, 7 fixed sweeps (quadratic convergence; uniform control flow).
  for (int sweep = 0; sweep < 7; ++sweep) {
    // (p,q,t)=(0,1,2): apt=a02, aqt=a12; V cols 0,1
    JROT(a00, a11, a01, a02, a12, v00, v01, v10, v11, v20, v21)
    // (p,q,t)=(0,2,1): apt=a01, aqt=a12; V cols 0,2
    JROT(a00, a22, a02, a01, a12, v00, v02, v10, v12, v20, v22)
    // (p,q,t)=(1,2,0): apt=a01, aqt=a02; V cols 1,2
    JROT(a11, a22, a12, a01, a02, v01, v02, v11, v12, v21, v22)
  }

  // Sort eigenpairs descending: col0=largest, col2=smallest.
  double e0 = a00, e1 = a11, e2 = a22;
  CSWAP(e0, e1, v00, v01, v10, v11, v20, v21)
  CSWAP(e0, e2, v00, v02, v10, v12, v20, v22)
  CSWAP(e1, e2, v01, v02, v11, v12, v21, v22)

  // u1 = normalize(H v1), v1 = (v00,v10,v20)
  double u1x = h00*v00 + h01*v10 + h02*v20;
  double u1y = h10*v00 + h11*v10 + h12*v20;
  double u1z = h20*v00 + h21*v10 + h22*v20;
  double n1 = sqrt(u1x*u1x + u1y*u1y + u1z*u1z);
  bool ok1 = n1 > 1e-150;
  double r1 = 1.0 / n1;                  // inf if degenerate; selected away
  u1x = ok1 ? u1x * r1 : 1.0;
  u1y = ok1 ? u1y * r1 : 0.0;
  u1z = ok1 ? u1z * r1 : 0.0;

  // u2 = normalize(H v2 orthogonalized against u1), v2 = (v01,v11,v21)
  double u2x = h00*v01 + h01*v11 + h02*v21;
  double u2y = h10*v01 + h11*v11 + h12*v21;
  double u2z = h20*v01 + h21*v11 + h22*v21;
  double d12 = u1x*u2x + u1y*u2y + u1z*u2z;
  u2x -= d12 * u1x; u2y -= d12 * u1y; u2z -= d12 * u1z;
  double n2 = sqrt(u2x*u2x + u2y*u2y + u2z*u2z);
  bool ok2 = n2 > 1e-150;
  // degenerate fallback: unit vector orthogonal to u1 (|u1|=1 so ng >= 0.43)
  double fx = (fabs(u1x) < 0.9) ? 1.0 : 0.0;
  double fy = 1.0 - fx;
  double dd = fx*u1x + fy*u1y;
  double gx = fx - dd*u1x, gy = fy - dd*u1y, gz = -dd*u1z;
  double rg = 1.0 / sqrt(gx*gx + gy*gy + gz*gz);
  double r2 = 1.0 / n2;                  // inf if degenerate; selected away
  u2x = ok2 ? u2x * r2 : gx * rg;
  u2y = ok2 ? u2y * r2 : gy * rg;
  u2z = ok2 ? u2z * r2 : gz * rg;

  // w3 = u1 x u2 (unit, right-handed)
  double w3x = u1y*u2z - u1z*u2y;
  double w3y = u1z*u2x - u1x*u2z;
  double w3z = u1x*u2y - u1y*u2x;

  // det(V) (sorted columns) = v1 . (v2 x v3); v3 = (v02,v12,v22)
  double cxx = v11*v22 - v21*v12;
  double cxy = v21*v02 - v01*v22;
  double cxz = v01*v12 - v11*v02;
  double dv = v00*cxx + v10*cxy + v20*cxz;
  dv = (dv >= 0.0) ? 1.0 : -1.0;

  // R[i][j] = v1[i]u1[j] + v2[i]u2[j] + dv*v3[i]w3[j]
  double R00 = v00*u1x + v01*u2x + dv*v02*w3x;
  double R01 = v00*u1y + v01*u2y + dv*v02*w3y;
  double R02 = v00*u1z + v01*u2z + dv*v02*w3z;
  double R10 = v10*u1x + v11*u2x + dv*v12*w3x;
  double R11 = v10*u1y + v11*u2y + dv*v12*w3y;
  double R12 = v10*u1z + v11*u2z + dv*v12*w3z;
  double R20 = v20*u1x + v21*u2x + dv*v22*w3x;
  double R21 = v20*u1y + v21*u2y + dv*v22*w3y;
  double R22 = v20*u1z + v21*u2z + dv*v22*w3z;

  R9[0] = (float)R00; R9[1] = (float)R01; R9[2] = (float)R02;
  R9[3] = (float)R10; R9[4] = (float)R11; R9[5] = (float)R12;
  R9[6] = (float)R20; R9[7] = (float)R21; R9[8] = (float)R22;
  t3[0] = (float)(tc0 - (R00*sc0 + R01*sc1 + R02*sc2));
  t3[1] = (float)(tc1 - (R10*sc0 + R11*sc1 + R12*sc2));
  t3[2] = (float)(tc2 - (R20*sc0 + R21*sc1 + R22*sc2));
}

// ---------------------------------------------------------------------------
// Kernel 1: 4 blocks per batch. Stage the 1024-pt chunk (28 KB) into LDS with
// coalesced global_load_lds (7 x 1KB wave-transactions per wave), then each
// thread reads its 4 points' 48B fragments from LDS and accumulates.
// ---------------------------------------------------------------------------
__global__ __launch_bounds__(THREADS) void wp_reduce_lds(const float* __restrict__ src,
                                                         const float* __restrict__ tgt,
                                                         const float* __restrict__ wts,
                                                         float* __restrict__ partials) {
  __shared__ float4 lds_w[CPTS / 4];       // 256 float4 =  4 KB
  __shared__ float4 lds_s[CPTS * 3 / 4];   // 768 float4 = 12 KB
  __shared__ float4 lds_t[CPTS * 3 / 4];   // 768 float4 = 12 KB
  __shared__ float red[64];

  const int bid = blockIdx.x;
  const int b = bid >> 2;          // batch
  const int c = bid & 3;           // chunk within batch
  const size_t poff = (size_t)b * NPTS + (size_t)c * CPTS;
  const float4* gw = (const float4*)(wts + poff);
  const float4* gs = (const float4*)(src + poff * 3);
  const float4* gt = (const float4*)(tgt + poff * 3);

  const int t = threadIdx.x;
  // 7 coalesced async 16B copies per thread (1 w + 3 src + 3 tgt)
  async_ld16(gw + t, lds_w + t);
#pragma unroll
  for (int k = 0; k < 3; ++k) async_ld16(gs + t + k * THREADS, lds_s + t + k * THREADS);
#pragma unroll
  for (int k = 0; k < 3; ++k) async_ld16(gt + t + k * THREADS, lds_t + t + k * THREADS);

  asm volatile("s_waitcnt vmcnt(0)" ::: "memory");
  __syncthreads();

  // Each thread consumes its 4 points from LDS (48B-strided ds_read_b128).
  float4 w4 = lds_w[t];
  float4 s0 = lds_s[t * 3], s1 = lds_s[t * 3 + 1], s2 = lds_s[t * 3 + 2];
  float4 r0 = lds_t[t * 3], r1 = lds_t[t * 3 + 1], r2 = lds_t[t * 3 + 2];

  float acc[16];
#pragma unroll
  for (int i = 0; i < 16; ++i) acc[i] = 0.f;
  accum_pts(w4, s0, s1, s2, r0, r1, r2, acc);

  reduce_block16(acc, red);
  if (t == 0) {
#pragma unroll
    for (int i = 0; i < 16; ++i) partials[(size_t)bid * 16 + i] = acc[i];
  }
}

// ---------------------------------------------------------------------------
// Kernel 2: one thread per batch: sum the 4 chunk-partials, scalar fp64 solve.
// ---------------------------------------------------------------------------
__global__ __launch_bounds__(64) void wp_solve(const float* __restrict__ partials,
                                               float* __restrict__ out) {
  const int b = blockIdx.x * 64 + threadIdx.x;
  if (b >= BATCH) return;
  float acc[16];
#pragma unroll
  for (int i = 0; i < 16; ++i) acc[i] = 0.f;
#pragma unroll
  for (int cch = 0; cch < CHUNKS; ++cch)
#pragma unroll
    for (int i = 0; i < 16; ++i)
      acc[i] += partials[(size_t)(b * CHUNKS + cch) * 16 + i];
  float R9[9], t3[3];
  solve_from_acc(acc, R9, t3);
#pragma unroll
  for (int i = 0; i < 9; ++i) out[(size_t)b * 9 + i] = R9[i];
#pragma unroll
  for (int i = 0; i < 3; ++i) out[(size_t)BATCH * 9 + (size_t)b * 3 + i] = t3[i];
}

// ---------------------------------------------------------------------------
// Fused fallback (only if ws_size is too small): one block per batch,
// register loads (no LDS staging).
// ---------------------------------------------------------------------------
__global__ __launch_bounds__(THREADS) void wp_fused(const float* __restrict__ src,
                                                    const float* __restrict__ tgt,
                                                    const float* __restrict__ wts,
                                                    float* __restrict__ out) {
  __shared__ float red[64];
  const int b = blockIdx.x;
  float acc[16];
#pragma unroll
  for (int i = 0; i < 16; ++i) acc[i] = 0.f;
  for (int c = 0; c < CHUNKS; ++c) {
    const size_t poff = (size_t)b * NPTS + (size_t)c * CPTS;
    const int p0 = threadIdx.x * 4;
    float4 w4 = *(const float4*)(wts + poff + p0);
    const float4* sp = (const float4*)(src + (poff + p0) * 3);
    const float4* tp = (const float4*)(tgt + (poff + p0) * 3);
    accum_pts(w4, sp[0], sp[1], sp[2], tp[0], tp[1], tp[2], acc);
  }
  reduce_block16(acc, red);
  if (threadIdx.x == 0) {
    float R9[9], t3[3];
    solve_from_acc(acc, R9, t3);
#pragma unroll
    for (int i = 0; i < 9; ++i) out[(size_t)b * 9 + i] = R9[i];
#pragma unroll
    for (int i = 0; i < 3; ++i) out[(size_t)BATCH * 9 + (size_t)b * 3 + i] = t3[i];
  }
}

extern "C" void kernel_launch(void* const* d_in, const int* in_sizes, int n_in,
                              void* d_out, int out_size, void* d_ws, size_t ws_size,
                              hipStream_t stream) {
  const float* src = (const float*)d_in[0];
  const float* tgt = (const float*)d_in[1];
  const float* wts = (const float*)d_in[2];
  float* out = (float*)d_out;

  if (ws_size >= (size_t)BATCH * CHUNKS * 16 * sizeof(float)) {
    float* partials = (float*)d_ws;
    wp_reduce_lds<<<BATCH * CHUNKS, THREADS, 0, stream>>>(src, tgt, wts, partials);
    wp_solve<<<(BATCH + 63) / 64, 64, 0, stream>>>(partials, out);
  } else {
    wp_fused<<<BATCH, THREADS, 0, stream>>>(src, tgt, wts, out);
  }
}

// Round 12
// 244.115 us; speedup vs baseline: 1.0049x; 1.0049x over previous
//
#include <hip/hip_runtime.h>
#include <math.h>

#define BATCH   2048
#define NPTS    4096
#define THREADS 256
#define NXCD    8
#define WTHRESH 0.5f
#define EPS     1e-5

// Native clang vector type — required by __builtin_nontemporal_load
// (HIP_vector_type float4 is a struct and is rejected).
typedef float f4 __attribute__((ext_vector_type(4)));

// Block-wide reduction of 16 floats; valid in acc[] of thread 0 afterwards.
__device__ __forceinline__ void reduce_block16(float* acc, float* red /*64 floats*/) {
#pragma unroll
  for (int off = 32; off > 0; off >>= 1) {
#pragma unroll
    for (int i = 0; i < 16; ++i) acc[i] += __shfl_down(acc[i], off, 64);
  }
  const int wave = threadIdx.x >> 6;
  const int lane = threadIdx.x & 63;
  if (lane == 0) {
#pragma unroll
    for (int i = 0; i < 16; ++i) red[wave * 16 + i] = acc[i];
  }
  __syncthreads();
  if (threadIdx.x == 0) {
#pragma unroll
    for (int w = 1; w < 4; ++w)
#pragma unroll
      for (int i = 0; i < 16; ++i) acc[i] += red[w * 16 + i];
  }
}

// ---------------------------------------------------------------------------
// Accumulate 16 sufficient statistics for 4 points given their registers.
// acc: [0]=W [1..3]=sum w*src [4..6]=sum w*tgt [7..15]=sum w*src_i*tgt_j
// ---------------------------------------------------------------------------
__device__ __forceinline__ void accum_pts(f4 w4, f4 s0, f4 s1, f4 s2,
                                          f4 r0, f4 r1, f4 r2, float* acc) {
  float ww[4] = {w4.x, w4.y, w4.z, w4.w};
  float ps[4][3] = {{s0.x, s0.y, s0.z}, {s0.w, s1.x, s1.y},
                    {s1.z, s1.w, s2.x}, {s2.y, s2.z, s2.w}};
  float qs[4][3] = {{r0.x, r0.y, r0.z}, {r0.w, r1.x, r1.y},
                    {r1.z, r1.w, r2.x}, {r2.y, r2.z, r2.w}};
#pragma unroll
  for (int i = 0; i < 4; ++i) {
    float w = (ww[i] < WTHRESH) ? 0.f : ww[i];
    acc[0] += w;
    float wp0 = w * ps[i][0], wp1 = w * ps[i][1], wp2 = w * ps[i][2];
    acc[1] += wp0; acc[2] += wp1; acc[3] += wp2;
    acc[4] += w * qs[i][0]; acc[5] += w * qs[i][1]; acc[6] += w * qs[i][2];
    acc[7]  += wp0 * qs[i][0]; acc[8]  += wp0 * qs[i][1]; acc[9]  += wp0 * qs[i][2];
    acc[10] += wp1 * qs[i][0]; acc[11] += wp1 * qs[i][1]; acc[12] += wp1 * qs[i][2];
    acc[13] += wp2 * qs[i][0]; acc[14] += wp2 * qs[i][1]; acc[15] += wp2 * qs[i][2];
  }
}

// ---------------------------------------------------------------------------
// fp64 3x3 Kabsch solve — fully scalarized (no arrays, no runtime indexing).
// R = v1 u1^T + v2 u2^T + det(V) * v3 (u1 x u2)^T   (verified: absmax 2e-3)
// ---------------------------------------------------------------------------
#define JROT(app, aqq, apq, apt, aqt, vp0, vq0, vp1, vq1, vp2, vq2)            \
  {                                                                            \
    bool go = fabs(apq) > 1e-300;                                              \
    double apq_s = go ? apq : 1.0;                                             \
    double theta = (aqq - app) / (2.0 * apq_s);                                \
    double tt = copysign(1.0, theta) / (fabs(theta) + sqrt(theta*theta + 1.0));\
    double cc = 1.0 / sqrt(tt*tt + 1.0);                                       \
    double ss = tt * cc;                                                       \
    cc = go ? cc : 1.0; ss = go ? ss : 0.0;                                    \
    double app_n = cc*cc*app - 2.0*cc*ss*apq + ss*ss*aqq;                      \
    double aqq_n = ss*ss*app + 2.0*cc*ss*apq + cc*cc*aqq;                      \
    double apt_n = cc*apt - ss*aqt;                                            \
    double aqt_n = ss*apt + cc*aqt;                                            \
    app = app_n; aqq = aqq_n; apq = 0.0; apt = apt_n; aqt = aqt_n;             \
    double tv;                                                                 \
    tv = vp0; vp0 = cc*tv - ss*vq0; vq0 = ss*tv + cc*vq0;                      \
    tv = vp1; vp1 = cc*tv - ss*vq1; vq1 = ss*tv + cc*vq1;                      \
    tv = vp2; vp2 = cc*tv - ss*vq2; vq2 = ss*tv + cc*vq2;                      \
  }

#define CSWAP(ea, eb, x0, y0, x1, y1, x2, y2)                                  \
  { bool sw = ea < eb; double td;                                              \
    td = ea; ea = sw ? eb : ea; eb = sw ? td : eb;                             \
    td = x0; x0 = sw ? y0 : x0; y0 = sw ? td : y0;                             \
    td = x1; x1 = sw ? y1 : x1; y1 = sw ? td : y1;                             \
    td = x2; x2 = sw ? y2 : x2; y2 = sw ? td : y2; }

__device__ void solve_from_acc(const float* acc, float* R9, float* t3) {
  const double W = acc[0];
  const double inv = 1.0 / (W + EPS);
  const double sc0 = acc[1] * inv, sc1 = acc[2] * inv, sc2 = acc[3] * inv;
  const double tc0 = acc[4] * inv, tc1 = acc[5] * inv, tc2 = acc[6] * inv;
  const double f = 2.0 - W * inv;

  const double h00 = acc[7]  * inv - sc0 * tc0 * f;
  const double h01 = acc[8]  * inv - sc0 * tc1 * f;
  const double h02 = acc[9]  * inv - sc0 * tc2 * f;
  const double h10 = acc[10] * inv - sc1 * tc0 * f;
  const double h11 = acc[11] * inv - sc1 * tc1 * f;
  const double h12 = acc[12] * inv - sc1 * tc2 * f;
  const double h20 = acc[13] * inv - sc2 * tc0 * f;
  const double h21 = acc[14] * inv - sc2 * tc1 * f;
  const double h22 = acc[15] * inv - sc2 * tc2 * f;

  double a00 = h00*h00 + h10*h10 + h20*h20;
  double a01 = h00*h01 + h10*h11 + h20*h21;
  double a02 = h00*h02 + h10*h12 + h20*h22;
  double a11 = h01*h01 + h11*h11 + h21*h21;
  double a12 = h01*h02 + h11*h12 + h21*h22;
  double a22 = h02*h02 + h12*h12 + h22*h22;

  double v00 = 1, v01 = 0, v02 = 0;
  double v10 = 0, v11 = 1, v12 = 0;
  double v20 = 0, v21 = 0, v22 = 1;

  for (int sweep = 0; sweep < 7; ++sweep) {
    JROT(a00, a11, a01, a02, a12, v00, v01, v10, v11, v20, v21)
    JROT(a00, a22, a02, a01, a12, v00, v02, v10, v12, v20, v22)
    JROT(a11, a22, a12, a01, a02, v01, v02, v11, v12, v21, v22)
  }

  double e0 = a00, e1 = a11, e2 = a22;
  CSWAP(e0, e1, v00, v01, v10, v11, v20, v21)
  CSWAP(e0, e2, v00, v02, v10, v12, v20, v22)
  CSWAP(e1, e2, v01, v02, v11, v12, v21, v22)

  double u1x = h00*v00 + h01*v10 + h02*v20;
  double u1y = h10*v00 + h11*v10 + h12*v20;
  double u1z = h20*v00 + h21*v10 + h22*v20;
  double n1 = sqrt(u1x*u1x + u1y*u1y + u1z*u1z);
  bool ok1 = n1 > 1e-150;
  double r1 = 1.0 / n1;
  u1x = ok1 ? u1x * r1 : 1.0;
  u1y = ok1 ? u1y * r1 : 0.0;
  u1z = ok1 ? u1z * r1 : 0.0;

  double u2x = h00*v01 + h01*v11 + h02*v21;
  double u2y = h10*v01 + h11*v11 + h12*v21;
  double u2z = h20*v01 + h21*v11 + h22*v21;
  double d12 = u1x*u2x + u1y*u2y + u1z*u2z;
  u2x -= d12 * u1x; u2y -= d12 * u1y; u2z -= d12 * u1z;
  double n2 = sqrt(u2x*u2x + u2y*u2y + u2z*u2z);
  bool ok2 = n2 > 1e-150;
  double fx = (fabs(u1x) < 0.9) ? 1.0 : 0.0;
  double fy = 1.0 - fx;
  double dd = fx*u1x + fy*u1y;
  double gx = fx - dd*u1x, gy = fy - dd*u1y, gz = -dd*u1z;
  double rg = 1.0 / sqrt(gx*gx + gy*gy + gz*gz);
  double r2 = 1.0 / n2;
  u2x = ok2 ? u2x * r2 : gx * rg;
  u2y = ok2 ? u2y * r2 : gy * rg;
  u2z = ok2 ? u2z * r2 : gz * rg;

  double w3x = u1y*u2z - u1z*u2y;
  double w3y = u1z*u2x - u1x*u2z;
  double w3z = u1x*u2y - u1y*u2x;

  double cxx = v11*v22 - v21*v12;
  double cxy = v21*v02 - v01*v22;
  double cxz = v01*v12 - v11*v02;
  double dv = v00*cxx + v10*cxy + v20*cxz;
  dv = (dv >= 0.0) ? 1.0 : -1.0;

  double R00 = v00*u1x + v01*u2x + dv*v02*w3x;
  double R01 = v00*u1y + v01*u2y + dv*v02*w3y;
  double R02 = v00*u1z + v01*u2z + dv*v02*w3z;
  double R10 = v10*u1x + v11*u2x + dv*v12*w3x;
  double R11 = v10*u1y + v11*u2y + dv*v12*w3y;
  double R12 = v10*u1z + v11*u2z + dv*v12*w3z;
  double R20 = v20*u1x + v21*u2x + dv*v22*w3x;
  double R21 = v20*u1y + v21*u2y + dv*v22*w3y;
  double R22 = v20*u1z + v21*u2z + dv*v22*w3z;

  R9[0] = (float)R00; R9[1] = (float)R01; R9[2] = (float)R02;
  R9[3] = (float)R10; R9[4] = (float)R11; R9[5] = (float)R12;
  R9[6] = (float)R20; R9[7] = (float)R21; R9[8] = (float)R22;
  t3[0] = (float)(tc0 - (R00*sc0 + R01*sc1 + R02*sc2));
  t3[1] = (float)(tc1 - (R10*sc0 + R11*sc1 + R12*sc2));
  t3[2] = (float)(tc2 - (R20*sc0 + R21*sc1 + R22*sc2));
}

// ---------------------------------------------------------------------------
// Fused kernel: one block per batch (XCD-swizzled), 4 point-quads per thread
// via NON-TEMPORAL AoS 16B loads, register accumulation, block reduce,
// thread-0 scalar fp64 solve, direct output write. No workspace needed.
// ---------------------------------------------------------------------------
__global__ __launch_bounds__(THREADS) void wp_fused(const float* __restrict__ src,
                                                    const float* __restrict__ tgt,
                                                    const float* __restrict__ wts,
                                                    float* __restrict__ out) {
  __shared__ float red[64];

  // Bijective XCD swizzle (BATCH % NXCD == 0): XCD x owns contiguous batches
  // [x*BATCH/NXCD, (x+1)*BATCH/NXCD) -> each XCD streams a contiguous ~29 MB.
  const int bid = blockIdx.x;
  const int b = (bid & (NXCD - 1)) * (BATCH / NXCD) + (bid >> 3);

  const int t = threadIdx.x;
  float acc[16];
#pragma unroll
  for (int i = 0; i < 16; ++i) acc[i] = 0.f;

#pragma unroll
  for (int c = 0; c < 4; ++c) {
    const size_t p0 = (size_t)b * NPTS + (size_t)c * 1024 + (size_t)t * 4;  // point idx
    const f4* gw = (const f4*)(wts + p0);
    const f4* gs = (const f4*)(src + p0 * 3);
    const f4* gt = (const f4*)(tgt + p0 * 3);
    f4 w4 = __builtin_nontemporal_load(gw);
    f4 s0 = __builtin_nontemporal_load(gs + 0);
    f4 s1 = __builtin_nontemporal_load(gs + 1);
    f4 s2 = __builtin_nontemporal_load(gs + 2);
    f4 r0 = __builtin_nontemporal_load(gt + 0);
    f4 r1 = __builtin_nontemporal_load(gt + 1);
    f4 r2 = __builtin_nontemporal_load(gt + 2);
    accum_pts(w4, s0, s1, s2, r0, r1, r2, acc);
  }

  reduce_block16(acc, red);

  if (t == 0) {
    float R9[9], t3[3];
    solve_from_acc(acc, R9, t3);
#pragma unroll
    for (int i = 0; i < 9; ++i) out[(size_t)b * 9 + i] = R9[i];
#pragma unroll
    for (int i = 0; i < 3; ++i) out[(size_t)BATCH * 9 + (size_t)b * 3 + i] = t3[i];
  }
}

extern "C" void kernel_launch(void* const* d_in, const int* in_sizes, int n_in,
                              void* d_out, int out_size, void* d_ws, size_t ws_size,
                              hipStream_t stream) {
  const float* src = (const float*)d_in[0];
  const float* tgt = (const float*)d_in[1];
  const float* wts = (const float*)d_in[2];
  float* out = (float*)d_out;
  wp_fused<<<BATCH, THREADS, 0, stream>>>(src, tgt, wts, out);
}